// Round 1
// baseline (159.997 us; speedup 1.0000x reference)
//
#include <hip/hip_runtime.h>

// SelfAttention fwd: qkv GEMM -> causal flash attention -> proj GEMM, bf16 MFMA.
// B=8 T=1024 C=768 H=12 HD=64.

typedef unsigned short u16;
typedef __bf16 bf16x8 __attribute__((ext_vector_type(8)));
typedef float  f32x4  __attribute__((ext_vector_type(4)));
typedef unsigned short u16x4 __attribute__((ext_vector_type(4)));
typedef unsigned short u16x8 __attribute__((ext_vector_type(8)));

#define DEV static __device__ __forceinline__

constexpr int B_ = 8, T_ = 1024, C_ = 768, H_ = 12, HD_ = 64;
constexpr int M1 = B_ * T_;   // 8192
constexpr int N1 = 3 * C_;    // 2304
constexpr int KD = C_;        // 768

DEV u16 f2bf(float f) {
    union { float f; unsigned u; } v; v.f = f;
    unsigned r = v.u + 0x7fffu + ((v.u >> 16) & 1u);   // RNE
    return (u16)(r >> 16);
}

DEV void gload16(const void* g, void* l) {
    // async global->LDS, 16B/lane; LDS dest = wave-uniform base + lane*16
    __builtin_amdgcn_global_load_lds(
        (const __attribute__((address_space(1))) unsigned*)g,
        (__attribute__((address_space(3))) unsigned*)l, 16, 0, 0);
}

// ---------------- convert kernels ----------------

__global__ __launch_bounds__(256) void cvt_x_kern(const float* __restrict__ x,
                                                  u16* __restrict__ xb, int n8) {
    int i = blockIdx.x * 256 + threadIdx.x;
    if (i >= n8) return;
    const float4* xf = (const float4*)x;
    float4 a = xf[i * 2], b = xf[i * 2 + 1];
    u16x8 o;
    o[0] = f2bf(a.x); o[1] = f2bf(a.y); o[2] = f2bf(a.z); o[3] = f2bf(a.w);
    o[4] = f2bf(b.x); o[5] = f2bf(b.y); o[6] = f2bf(b.z); o[7] = f2bf(b.w);
    *(u16x8*)(xb + (size_t)i * 8) = o;
}

// W [K][N] fp32 row-major -> Wt [N][K] bf16 row-major
__global__ __launch_bounds__(256) void cvt_wT_kern(const float* __restrict__ W,
                                                   u16* __restrict__ Wt, int K, int N) {
    __shared__ float tile[32][33];
    int n0 = blockIdx.x * 32, k0 = blockIdx.y * 32;
    int tx = threadIdx.x & 31, ty = threadIdx.x >> 5;  // 32 x 8
#pragma unroll
    for (int i = 0; i < 4; i++) {
        int k = ty * 4 + i;
        tile[k][tx] = W[(size_t)(k0 + k) * N + n0 + tx];
    }
    __syncthreads();
#pragma unroll
    for (int i = 0; i < 4; i++) {
        int n = ty * 4 + i;
        Wt[(size_t)(n0 + n) * K + k0 + tx] = f2bf(tile[tx][n]);
    }
}

// ---------------- GEMM (A [M][K] bf16, Bt [N][K] bf16), 128x128 tile, BK=64 ----------------
// MODE 0: qkv epilogue (scatter q*0.125/k/vT).  MODE 1: fp32 out + bias.

template <int MODE>
__global__ __launch_bounds__(256, 2) void gemm_bt_kern(
    const u16* __restrict__ A, const u16* __restrict__ Bt,
    const float* __restrict__ bias, int nBN,
    u16* __restrict__ qw, u16* __restrict__ kw, u16* __restrict__ vw,
    float* __restrict__ out) {
    __shared__ u16 ldsA[128 * 64];
    __shared__ u16 ldsB[128 * 64];
    const int bm = blockIdx.x / nBN, bn = blockIdx.x % nBN;
    const int m0 = bm * 128, n0 = bn * 128;
    const int t = threadIdx.x;
    const int lane = t & 63, w = t >> 6;
    const int wr = w >> 1, wc = w & 1;
    const int l15 = lane & 15, lhi = lane >> 4;
    // staging: thread t covers tile-row (t>>3)+s*32, 16B chunk (t&7)
    const int srow = t >> 3;
    const int scb = ((t & 7) << 4) ^ ((srow & 7) << 4);  // pre-swizzled source chunk
    const char* Ab = (const char*)(A + (size_t)(m0 + srow) * KD) + scb;
    const char* Bb = (const char*)(Bt + (size_t)(n0 + srow) * KD) + scb;
    char* lA = (char*)ldsA + w * 1024;  // uniform wave base; HW adds lane*16
    char* lB = (char*)ldsB + w * 1024;

    f32x4 acc[4][4] = {};

    for (int k0 = 0; k0 < KD; k0 += 64) {
#pragma unroll
        for (int s = 0; s < 4; s++) {
            gload16(Ab + (size_t)k0 * 2 + (size_t)s * 32 * KD * 2, lA + s * 4096);
            gload16(Bb + (size_t)k0 * 2 + (size_t)s * 32 * KD * 2, lB + s * 4096);
        }
        __syncthreads();
#pragma unroll
        for (int kk = 0; kk < 2; kk++) {
            bf16x8 af[4], bfr[4];
#pragma unroll
            for (int i = 0; i < 4; i++) {
                int rowA = wr * 64 + i * 16 + l15;
                af[i] = *(const bf16x8*)((const char*)ldsA + rowA * 128 +
                                         ((kk * 64 + lhi * 16) ^ ((rowA & 7) << 4)));
                int rowB = wc * 64 + i * 16 + l15;
                bfr[i] = *(const bf16x8*)((const char*)ldsB + rowB * 128 +
                                          ((kk * 64 + lhi * 16) ^ ((rowB & 7) << 4)));
            }
#pragma unroll
            for (int fm = 0; fm < 4; fm++)
#pragma unroll
                for (int fn = 0; fn < 4; fn++)
                    acc[fm][fn] = __builtin_amdgcn_mfma_f32_16x16x32_bf16(
                        af[fm], bfr[fn], acc[fm][fn], 0, 0, 0);
        }
        __syncthreads();
    }

    if constexpr (MODE == 1) {
#pragma unroll
        for (int fm = 0; fm < 4; fm++) {
            const int mb = m0 + wr * 64 + fm * 16 + lhi * 4;
#pragma unroll
            for (int fn = 0; fn < 4; fn++) {
                const int n = n0 + wc * 64 + fn * 16 + l15;
                const float bv = bias[n];
#pragma unroll
                for (int r = 0; r < 4; r++)
                    out[(size_t)(mb + r) * C_ + n] = acc[fm][fn][r] + bv;
            }
        }
    } else {
#pragma unroll
        for (int fn = 0; fn < 4; fn++) {
            const int c0 = n0 + wc * 64 + fn * 16;
            const int h3 = c0 >> 6;                 // wave-uniform head index
            const int d = (c0 & 63) + l15;
            const float bv = bias[c0 + l15];
#pragma unroll
            for (int fm = 0; fm < 4; fm++) {
                const int mb = m0 + wr * 64 + fm * 16 + lhi * 4;
                const int b = mb >> 10, tq = mb & 1023;
                if (h3 < H_) {
                    u16* dst = qw + ((size_t)(b * H_ + h3) * T_ + tq) * HD_ + d;
#pragma unroll
                    for (int r = 0; r < 4; r++)
                        dst[r * HD_] = f2bf((acc[fm][fn][r] + bv) * 0.125f);
                } else if (h3 < 2 * H_) {
                    u16* dst = kw + ((size_t)(b * H_ + (h3 - H_)) * T_ + tq) * HD_ + d;
#pragma unroll
                    for (int r = 0; r < 4; r++)
                        dst[r * HD_] = f2bf(acc[fm][fn][r] + bv);
                } else {
                    u16x4 p;
#pragma unroll
                    for (int r = 0; r < 4; r++) p[r] = f2bf(acc[fm][fn][r] + bv);
                    *(u16x4*)(vw + ((size_t)(b * H_ + (h3 - 2 * H_)) * HD_ + d) * T_ + tq) = p;
                }
            }
        }
    }
}

// ---------------- causal flash attention ----------------
// grid: (b,h) * 16 q-tiles of 64.  4 waves x 16 q-rows.  KV tile = 64.
// q already scaled by 1/8.  k [bh][t][64], vT [bh][64][t], out ao [b*t][h*64+d] bf16.

__global__ __launch_bounds__(256, 2) void attn_fwd_kern(
    const u16* __restrict__ qg, const u16* __restrict__ kg,
    const u16* __restrict__ vg, u16* __restrict__ ao) {
    __shared__ u16 qld[64 * 64], kld[64 * 64], vld[64 * 64];
    __shared__ u16 pld[4][16 * 72];  // +16B pad per row -> 2-way conflicts only
    const int bh = blockIdx.x >> 4, qt = blockIdx.x & 15;
    const int t = threadIdx.x, lane = t & 63, w = t >> 6;
    const int l15 = lane & 15, lhi = lane >> 4;
    const int srow = t >> 3;
    const int scb = ((t & 7) << 4) ^ ((srow & 7) << 4);
    const char* qb = (const char*)(qg + (size_t)bh * T_ * HD_);
    const char* kb = (const char*)(kg + (size_t)bh * T_ * HD_);
    const char* vb = (const char*)(vg + (size_t)bh * HD_ * T_);

#pragma unroll
    for (int s = 0; s < 2; s++)
        gload16(qb + (size_t)(qt * 64 + srow + s * 32) * 128 + scb,
                (char*)qld + w * 1024 + s * 4096);

    f32x4 acc[4] = {};
    float mst[4] = {-1e30f, -1e30f, -1e30f, -1e30f};
    float lst[4] = {0.f, 0.f, 0.f, 0.f};

    for (int kvt = 0; kvt <= qt; kvt++) {
#pragma unroll
        for (int s = 0; s < 2; s++) {
            int row = srow + s * 32;
            gload16(kb + (size_t)(kvt * 64 + row) * 128 + scb,
                    (char*)kld + w * 1024 + s * 4096);
            gload16(vb + (size_t)row * 2048 + kvt * 128 + scb,
                    (char*)vld + w * 1024 + s * 4096);
        }
        __syncthreads();  // staging (and Q on first iter) complete

        // S = Q K^T  (16 q-rows x 64 kv)
        f32x4 s4[4] = {};
#pragma unroll
        for (int kk = 0; kk < 2; kk++) {
            const int rq = w * 16 + l15;
            bf16x8 aq = *(const bf16x8*)((const char*)qld + rq * 128 +
                                         ((kk * 64 + lhi * 16) ^ ((rq & 7) << 4)));
#pragma unroll
            for (int fc = 0; fc < 4; fc++) {
                const int rk = fc * 16 + l15;
                bf16x8 bk = *(const bf16x8*)((const char*)kld + rk * 128 +
                                             ((kk * 64 + lhi * 16) ^ ((rk & 7) << 4)));
                s4[fc] = __builtin_amdgcn_mfma_f32_16x16x32_bf16(aq, bk, s4[fc], 0, 0, 0);
            }
        }
        if (kvt == qt) {  // mask only diagonal tile
            const int qrow = qt * 64 + w * 16 + lhi * 4;
#pragma unroll
            for (int fc = 0; fc < 4; fc++) {
                const int kcol = kvt * 64 + fc * 16 + l15;
#pragma unroll
                for (int r = 0; r < 4; r++)
                    if (kcol > qrow + r) s4[fc][r] = -1e30f;
            }
        }
        // online softmax (rows live in 16-lane groups)
        float rmax[4], corr[4], rsum[4];
#pragma unroll
        for (int r = 0; r < 4; r++) {
            rmax[r] = fmaxf(fmaxf(s4[0][r], s4[1][r]), fmaxf(s4[2][r], s4[3][r]));
#pragma unroll
            for (int m = 1; m < 16; m <<= 1)
                rmax[r] = fmaxf(rmax[r], __shfl_xor(rmax[r], m, 16));
            float mn = fmaxf(mst[r], rmax[r]);
            corr[r] = __expf(mst[r] - mn);
            mst[r] = mn;
        }
#pragma unroll
        for (int fc = 0; fc < 4; fc++)
#pragma unroll
            for (int r = 0; r < 4; r++)
                s4[fc][r] = __expf(s4[fc][r] - mst[r]);
#pragma unroll
        for (int r = 0; r < 4; r++) {
            rsum[r] = s4[0][r] + s4[1][r] + s4[2][r] + s4[3][r];
#pragma unroll
            for (int m = 1; m < 16; m <<= 1)
                rsum[r] += __shfl_xor(rsum[r], m, 16);
            lst[r] = lst[r] * corr[r] + rsum[r];
        }
#pragma unroll
        for (int fd = 0; fd < 4; fd++)
#pragma unroll
            for (int r = 0; r < 4; r++) acc[fd][r] *= corr[r];
        // P -> LDS (per-wave region), relayout D-frag -> A-frag
        u16* pw = pld[w];
#pragma unroll
        for (int fc = 0; fc < 4; fc++)
#pragma unroll
            for (int r = 0; r < 4; r++)
                pw[(lhi * 4 + r) * 72 + fc * 16 + l15] = f2bf(s4[fc][r]);
        __syncthreads();  // P visible (and all kld reads done)

        // O += P V
#pragma unroll
        for (int kk = 0; kk < 2; kk++) {
            bf16x8 ap = *(const bf16x8*)((const char*)pld[w] + l15 * 144 + kk * 64 + lhi * 16);
#pragma unroll
            for (int fd = 0; fd < 4; fd++) {
                const int rd = fd * 16 + l15;
                bf16x8 bv = *(const bf16x8*)((const char*)vld + rd * 128 +
                                             ((kk * 64 + lhi * 16) ^ ((rd & 7) << 4)));
                acc[fd] = __builtin_amdgcn_mfma_f32_16x16x32_bf16(ap, bv, acc[fd], 0, 0, 0);
            }
        }
        __syncthreads();  // protect kld/vld/pld before next staging
    }

    const int b = bh / H_, h = bh % H_;
#pragma unroll
    for (int r = 0; r < 4; r++) {
        const int tq = qt * 64 + w * 16 + lhi * 4 + r;
        const float inv = 1.0f / lst[r];
#pragma unroll
        for (int fd = 0; fd < 4; fd++)
            ao[((size_t)(b * T_ + tq)) * C_ + h * 64 + fd * 16 + l15] =
                f2bf(acc[fd][r] * inv);
    }
}

// ---------------- launch ----------------

extern "C" void kernel_launch(void* const* d_in, const int* in_sizes, int n_in,
                              void* d_out, int out_size, void* d_ws, size_t ws_size,
                              hipStream_t stream) {
    const float* x     = (const float*)d_in[0];
    // d_in[1] = mask (causal tril) -- structure hard-coded
    const float* Wqkv  = (const float*)d_in[2];
    const float* bqkv  = (const float*)d_in[3];
    const float* Wproj = (const float*)d_in[4];
    const float* bproj = (const float*)d_in[5];
    float* out = (float*)d_out;

    char* ws = (char*)d_ws;
    u16* xb     = (u16*)(ws);                 // 12,582,912 B
    u16* wqkvT  = (u16*)(ws + 12582912);      //  3,538,944 B
    u16* wprojT = (u16*)(ws + 16121856);      //  1,179,648 B
    u16* qw     = (u16*)(ws + 17301504);      // 12,582,912 B  [B,H,T,64] (pre-scaled)
    u16* kw     = (u16*)(ws + 29884416);      // 12,582,912 B  [B,H,T,64]
    u16* vw     = (u16*)(ws + 42467328);      // 12,582,912 B  [B,H,64,T] (transposed)
    u16* ao     = (u16*)(ws + 55050240);      // 12,582,912 B  [B*T, C]

    cvt_x_kern<<<(M1 * C_ / 8 + 255) / 256, 256, 0, stream>>>(x, xb, M1 * C_ / 8);
    cvt_wT_kern<<<dim3(N1 / 32, KD / 32), 256, 0, stream>>>(Wqkv, wqkvT, KD, N1);
    cvt_wT_kern<<<dim3(C_ / 32, KD / 32), 256, 0, stream>>>(Wproj, wprojT, KD, C_);

    gemm_bt_kern<0><<<(M1 / 128) * (N1 / 128), 256, 0, stream>>>(
        xb, wqkvT, bqkv, N1 / 128, qw, kw, vw, nullptr);

    attn_fwd_kern<<<B_ * H_ * (T_ / 64), 256, 0, stream>>>(qw, kw, vw, ao);

    gemm_bt_kern<1><<<(M1 / 128) * (C_ / 128), 256, 0, stream>>>(
        ao, wprojT, bproj, C_ / 128, nullptr, nullptr, nullptr, out);
}

// Round 2
// 129.415 us; speedup vs baseline: 1.2363x; 1.2363x over previous
//
#include <hip/hip_runtime.h>

// SelfAttention fwd: qkv GEMM -> causal flash attention -> proj GEMM, bf16 MFMA.
// B=8 T=1024 C=768 H=12 HD=64.

typedef unsigned short u16;
typedef __bf16 bf16x8 __attribute__((ext_vector_type(8)));
typedef float  f32x4  __attribute__((ext_vector_type(4)));
typedef unsigned short u16x4 __attribute__((ext_vector_type(4)));
typedef unsigned short u16x8 __attribute__((ext_vector_type(8)));

#define DEV static __device__ __forceinline__

constexpr int B_ = 8, T_ = 1024, C_ = 768, H_ = 12, HD_ = 64;
constexpr int M1 = B_ * T_;   // 8192
constexpr int N1 = 3 * C_;    // 2304
constexpr int KD = C_;        // 768

DEV u16 f2bf(float f) {
    union { float f; unsigned u; } v; v.f = f;
    unsigned r = v.u + 0x7fffu + ((v.u >> 16) & 1u);   // RNE
    return (u16)(r >> 16);
}

DEV void gload16(const void* g, void* l) {
    // async global->LDS, 16B/lane; LDS dest = wave-uniform base + lane*16
    __builtin_amdgcn_global_load_lds(
        (const __attribute__((address_space(1))) unsigned*)g,
        (__attribute__((address_space(3))) unsigned*)l, 16, 0, 0);
}

// ---------------- convert kernels ----------------

__global__ __launch_bounds__(256) void cvt_x_kern(const float* __restrict__ x,
                                                  u16* __restrict__ xb, int n8) {
    int i = blockIdx.x * 256 + threadIdx.x;
    if (i >= n8) return;
    const float4* xf = (const float4*)x;
    float4 a = xf[i * 2], b = xf[i * 2 + 1];
    u16x8 o;
    o[0] = f2bf(a.x); o[1] = f2bf(a.y); o[2] = f2bf(a.z); o[3] = f2bf(a.w);
    o[4] = f2bf(b.x); o[5] = f2bf(b.y); o[6] = f2bf(b.z); o[7] = f2bf(b.w);
    *(u16x8*)(xb + (size_t)i * 8) = o;
}

// W [K][N] fp32 row-major -> Wt [N][K] bf16 row-major
__global__ __launch_bounds__(256) void cvt_wT_kern(const float* __restrict__ W,
                                                   u16* __restrict__ Wt, int K, int N) {
    __shared__ float tile[32][33];
    int n0 = blockIdx.x * 32, k0 = blockIdx.y * 32;
    int tx = threadIdx.x & 31, ty = threadIdx.x >> 5;  // 32 x 8
#pragma unroll
    for (int i = 0; i < 4; i++) {
        int k = ty * 4 + i;
        tile[k][tx] = W[(size_t)(k0 + k) * N + n0 + tx];
    }
    __syncthreads();
#pragma unroll
    for (int i = 0; i < 4; i++) {
        int n = ty * 4 + i;
        Wt[(size_t)(n0 + n) * K + k0 + tx] = f2bf(tile[tx][n]);
    }
}

// ---------------- GEMM (A [M][K] bf16, Bt [N][K] bf16), 128x128 tile, BK=64 ----------------
// MODE 0: qkv epilogue (scatter q*0.125/k/vT).  MODE 1: fp32 out + bias.

template <int MODE>
__global__ __launch_bounds__(256, 2) void gemm_bt_kern(
    const u16* __restrict__ A, const u16* __restrict__ Bt,
    const float* __restrict__ bias, int nBN,
    u16* __restrict__ qw, u16* __restrict__ kw, u16* __restrict__ vw,
    float* __restrict__ out) {
    __shared__ u16 ldsA[128 * 64];
    __shared__ u16 ldsB[128 * 64];
    const int bm = blockIdx.x / nBN, bn = blockIdx.x % nBN;
    const int m0 = bm * 128, n0 = bn * 128;
    const int t = threadIdx.x;
    const int lane = t & 63, w = t >> 6;
    const int wr = w >> 1, wc = w & 1;
    const int l15 = lane & 15, lhi = lane >> 4;
    // staging: thread t covers tile-row (t>>3)+s*32, 16B chunk (t&7)
    const int srow = t >> 3;
    const int scb = ((t & 7) << 4) ^ ((srow & 7) << 4);  // pre-swizzled source chunk
    const char* Ab = (const char*)(A + (size_t)(m0 + srow) * KD) + scb;
    const char* Bb = (const char*)(Bt + (size_t)(n0 + srow) * KD) + scb;
    char* lA = (char*)ldsA + w * 1024;  // uniform wave base; HW adds lane*16
    char* lB = (char*)ldsB + w * 1024;

    f32x4 acc[4][4] = {};

    for (int k0 = 0; k0 < KD; k0 += 64) {
#pragma unroll
        for (int s = 0; s < 4; s++) {
            gload16(Ab + (size_t)k0 * 2 + (size_t)s * 32 * KD * 2, lA + s * 4096);
            gload16(Bb + (size_t)k0 * 2 + (size_t)s * 32 * KD * 2, lB + s * 4096);
        }
        __syncthreads();
#pragma unroll
        for (int kk = 0; kk < 2; kk++) {
            bf16x8 af[4], bfr[4];
#pragma unroll
            for (int i = 0; i < 4; i++) {
                int rowA = wr * 64 + i * 16 + l15;
                af[i] = *(const bf16x8*)((const char*)ldsA + rowA * 128 +
                                         ((kk * 64 + lhi * 16) ^ ((rowA & 7) << 4)));
                int rowB = wc * 64 + i * 16 + l15;
                bfr[i] = *(const bf16x8*)((const char*)ldsB + rowB * 128 +
                                          ((kk * 64 + lhi * 16) ^ ((rowB & 7) << 4)));
            }
#pragma unroll
            for (int fm = 0; fm < 4; fm++)
#pragma unroll
                for (int fn = 0; fn < 4; fn++)
                    acc[fm][fn] = __builtin_amdgcn_mfma_f32_16x16x32_bf16(
                        af[fm], bfr[fn], acc[fm][fn], 0, 0, 0);
        }
        __syncthreads();
    }

    if constexpr (MODE == 1) {
#pragma unroll
        for (int fm = 0; fm < 4; fm++) {
            const int mb = m0 + wr * 64 + fm * 16 + lhi * 4;
#pragma unroll
            for (int fn = 0; fn < 4; fn++) {
                const int n = n0 + wc * 64 + fn * 16 + l15;
                const float bv = bias[n];
#pragma unroll
                for (int r = 0; r < 4; r++)
                    out[(size_t)(mb + r) * C_ + n] = acc[fm][fn][r] + bv;
            }
        }
    } else {
#pragma unroll
        for (int fn = 0; fn < 4; fn++) {
            const int c0 = n0 + wc * 64 + fn * 16;
            const int h3 = c0 >> 6;                 // wave-uniform head index
            const int d = (c0 & 63) + l15;
            const float bv = bias[c0 + l15];
#pragma unroll
            for (int fm = 0; fm < 4; fm++) {
                const int mb = m0 + wr * 64 + fm * 16 + lhi * 4;
                const int b = mb >> 10, tq = mb & 1023;
                if (h3 < H_) {
                    u16* dst = qw + ((size_t)(b * H_ + h3) * T_ + tq) * HD_ + d;
#pragma unroll
                    for (int r = 0; r < 4; r++)
                        dst[r * HD_] = f2bf((acc[fm][fn][r] + bv) * 0.125f);
                } else if (h3 < 2 * H_) {
                    u16* dst = kw + ((size_t)(b * H_ + (h3 - H_)) * T_ + tq) * HD_ + d;
#pragma unroll
                    for (int r = 0; r < 4; r++)
                        dst[r * HD_] = f2bf(acc[fm][fn][r] + bv);
                } else {
                    u16x4 p;
#pragma unroll
                    for (int r = 0; r < 4; r++) p[r] = f2bf(acc[fm][fn][r] + bv);
                    *(u16x4*)(vw + ((size_t)(b * H_ + (h3 - 2 * H_)) * HD_ + d) * T_ + tq) = p;
                }
            }
        }
    }
}

// ---------------- causal flash attention ----------------
// QBLK=128 (4 waves x 32 q-rows), KVBLK=64, double-buffered K/V, 1 barrier/tile.
// grid swizzle: same-bh blocks share bid%8 (same XCD L2); qt descending.
// q pre-scaled by 1/8.  k [bh][t][64], vT [bh][64][t], out ao [b*t][h*64+d] bf16.

__global__ __launch_bounds__(256, 2) void attn_fwd_kern(
    const u16* __restrict__ qg, const u16* __restrict__ kg,
    const u16* __restrict__ vg, u16* __restrict__ ao) {
    __shared__ u16 qld[128 * 64];
    __shared__ u16 kld[2][64 * 64];
    __shared__ u16 vld[2][64 * 64];
    __shared__ u16 pld[4][16 * 72];  // per-wave P relayout buffer (+16B pad)
    const int n = blockIdx.x;
    const int bh = (n & 7) + 8 * ((n >> 3) % 12);
    const int qt = 7 - n / 96;            // big-work blocks first
    const int t = threadIdx.x, lane = t & 63, w = t >> 6;
    const int l15 = lane & 15, lhi = lane >> 4;
    const int srow = t >> 3;
    const int scb = ((t & 7) << 4) ^ ((srow & 7) << 4);
    const char* qb = (const char*)(qg + (size_t)bh * T_ * HD_);
    const char* kb = (const char*)(kg + (size_t)bh * T_ * HD_);
    const char* vb = (const char*)(vg + (size_t)bh * HD_ * T_);

    // stage Q (128 rows) and K/V tile 0
#pragma unroll
    for (int s = 0; s < 4; s++)
        gload16(qb + (size_t)(qt * 128 + srow + s * 32) * 128 + scb,
                (char*)qld + w * 1024 + s * 4096);
#pragma unroll
    for (int s = 0; s < 2; s++) {
        gload16(kb + (size_t)(srow + s * 32) * 128 + scb,
                (char*)kld[0] + w * 1024 + s * 4096);
        gload16(vb + (size_t)(srow + s * 32) * 2048 + scb,
                (char*)vld[0] + w * 1024 + s * 4096);
    }
    __syncthreads();

    f32x4 acc[2][4] = {};
    float mst[2][4], lst[2][4];
#pragma unroll
    for (int g = 0; g < 2; g++)
#pragma unroll
        for (int r = 0; r < 4; r++) { mst[g][r] = -1e30f; lst[g][r] = 0.f; }

    const int ntiles = 2 * qt + 2;
    for (int kvt = 0; kvt < ntiles; kvt++) {
        const int cur = kvt & 1;
        if (kvt + 1 < ntiles) {  // prefetch next K/V tile (latency hidden by compute)
#pragma unroll
            for (int s = 0; s < 2; s++) {
                gload16(kb + (size_t)((kvt + 1) * 64 + srow + s * 32) * 128 + scb,
                        (char*)kld[cur ^ 1] + w * 1024 + s * 4096);
                gload16(vb + (size_t)(srow + s * 32) * 2048 + (kvt + 1) * 128 + scb,
                        (char*)vld[cur ^ 1] + w * 1024 + s * 4096);
            }
        }
#pragma unroll
        for (int g = 0; g < 2; g++) {
            // S = Q K^T  (16 q-rows x 64 kv)
            f32x4 s4[4] = {};
#pragma unroll
            for (int kk = 0; kk < 2; kk++) {
                const int rq = w * 32 + g * 16 + l15;
                bf16x8 aq = *(const bf16x8*)((const char*)qld + rq * 128 +
                                             ((kk * 64 + lhi * 16) ^ ((rq & 7) << 4)));
#pragma unroll
                for (int fc = 0; fc < 4; fc++) {
                    const int rk = fc * 16 + l15;
                    bf16x8 bk = *(const bf16x8*)((const char*)kld[cur] + rk * 128 +
                                                 ((kk * 64 + lhi * 16) ^ ((rk & 7) << 4)));
                    s4[fc] = __builtin_amdgcn_mfma_f32_16x16x32_bf16(aq, bk, s4[fc], 0, 0, 0);
                }
            }
            const int qrow0 = qt * 128 + w * 32 + g * 16;
            if (kvt * 64 + 63 > qrow0) {  // diagonal-overlap tile: apply causal mask
#pragma unroll
                for (int fc = 0; fc < 4; fc++) {
                    const int kcol = kvt * 64 + fc * 16 + l15;
#pragma unroll
                    for (int r = 0; r < 4; r++)
                        if (kcol > qrow0 + lhi * 4 + r) s4[fc][r] = -1e30f;
                }
            }
            // online softmax (rows live in 16-lane groups)
            float rmax[4], corr[4], rsum[4];
#pragma unroll
            for (int r = 0; r < 4; r++) {
                rmax[r] = fmaxf(fmaxf(s4[0][r], s4[1][r]), fmaxf(s4[2][r], s4[3][r]));
#pragma unroll
                for (int m = 1; m < 16; m <<= 1)
                    rmax[r] = fmaxf(rmax[r], __shfl_xor(rmax[r], m, 16));
                float mn = fmaxf(mst[g][r], rmax[r]);
                corr[r] = __expf(mst[g][r] - mn);
                mst[g][r] = mn;
            }
#pragma unroll
            for (int fc = 0; fc < 4; fc++)
#pragma unroll
                for (int r = 0; r < 4; r++)
                    s4[fc][r] = __expf(s4[fc][r] - mst[g][r]);
#pragma unroll
            for (int r = 0; r < 4; r++) {
                rsum[r] = s4[0][r] + s4[1][r] + s4[2][r] + s4[3][r];
#pragma unroll
                for (int m = 1; m < 16; m <<= 1)
                    rsum[r] += __shfl_xor(rsum[r], m, 16);
                lst[g][r] = lst[g][r] * corr[r] + rsum[r];
            }
#pragma unroll
            for (int fd = 0; fd < 4; fd++)
#pragma unroll
                for (int r = 0; r < 4; r++) acc[g][fd][r] *= corr[r];
            // P -> per-wave LDS region (intra-wave dep only; no barrier needed)
            u16* pw = pld[w];
#pragma unroll
            for (int fc = 0; fc < 4; fc++)
#pragma unroll
                for (int r = 0; r < 4; r++)
                    pw[(lhi * 4 + r) * 72 + fc * 16 + l15] = f2bf(s4[fc][r]);
            // O += P V
#pragma unroll
            for (int kk = 0; kk < 2; kk++) {
                bf16x8 ap = *(const bf16x8*)((const char*)pld[w] + l15 * 144 + kk * 64 + lhi * 16);
#pragma unroll
                for (int fd = 0; fd < 4; fd++) {
                    const int rd = fd * 16 + l15;
                    bf16x8 bv = *(const bf16x8*)((const char*)vld[cur] + rd * 128 +
                                                 ((kk * 64 + lhi * 16) ^ ((rd & 7) << 4)));
                    acc[g][fd] = __builtin_amdgcn_mfma_f32_16x16x32_bf16(ap, bv, acc[g][fd], 0, 0, 0);
                }
            }
        }
        __syncthreads();  // prefetched tile ready; all waves done with buf[cur]
    }

    const int b = bh / H_, h = bh % H_;
#pragma unroll
    for (int g = 0; g < 2; g++)
#pragma unroll
        for (int r = 0; r < 4; r++) {
            const int tq = qt * 128 + w * 32 + g * 16 + lhi * 4 + r;
            const float inv = 1.0f / lst[g][r];
#pragma unroll
            for (int fd = 0; fd < 4; fd++)
                ao[((size_t)(b * T_ + tq)) * C_ + h * 64 + fd * 16 + l15] =
                    f2bf(acc[g][fd][r] * inv);
        }
}

// ---------------- launch ----------------

extern "C" void kernel_launch(void* const* d_in, const int* in_sizes, int n_in,
                              void* d_out, int out_size, void* d_ws, size_t ws_size,
                              hipStream_t stream) {
    const float* x     = (const float*)d_in[0];
    // d_in[1] = mask (causal tril) -- structure hard-coded
    const float* Wqkv  = (const float*)d_in[2];
    const float* bqkv  = (const float*)d_in[3];
    const float* Wproj = (const float*)d_in[4];
    const float* bproj = (const float*)d_in[5];
    float* out = (float*)d_out;

    char* ws = (char*)d_ws;
    u16* xb     = (u16*)(ws);                 // 12,582,912 B
    u16* wqkvT  = (u16*)(ws + 12582912);      //  3,538,944 B
    u16* wprojT = (u16*)(ws + 16121856);      //  1,179,648 B
    u16* qw     = (u16*)(ws + 17301504);      // 12,582,912 B  [B,H,T,64] (pre-scaled)
    u16* kw     = (u16*)(ws + 29884416);      // 12,582,912 B  [B,H,T,64]
    u16* vw     = (u16*)(ws + 42467328);      // 12,582,912 B  [B,H,64,T] (transposed)
    u16* ao     = (u16*)(ws + 55050240);      // 12,582,912 B  [B*T, C]

    cvt_x_kern<<<(M1 * C_ / 8 + 255) / 256, 256, 0, stream>>>(x, xb, M1 * C_ / 8);
    cvt_wT_kern<<<dim3(N1 / 32, KD / 32), 256, 0, stream>>>(Wqkv, wqkvT, KD, N1);
    cvt_wT_kern<<<dim3(C_ / 32, KD / 32), 256, 0, stream>>>(Wproj, wprojT, KD, C_);

    gemm_bt_kern<0><<<(M1 / 128) * (N1 / 128), 256, 0, stream>>>(
        xb, wqkvT, bqkv, N1 / 128, qw, kw, vw, nullptr);

    attn_fwd_kern<<<B_ * H_ * (T_ / 128), 256, 0, stream>>>(qw, kw, vw, ao);

    gemm_bt_kern<1><<<(M1 / 128) * (C_ / 128), 256, 0, stream>>>(
        ao, wprojT, bproj, C_ / 128, nullptr, nullptr, nullptr, out);
}

// Round 3
// 125.281 us; speedup vs baseline: 1.2771x; 1.0330x over previous
//
#include <hip/hip_runtime.h>

// SelfAttention fwd: qkv GEMM -> causal flash attention -> proj GEMM, bf16 MFMA.
// B=8 T=1024 C=768 H=12 HD=64.

typedef unsigned short u16;
typedef __bf16 bf16x8 __attribute__((ext_vector_type(8)));
typedef float  f32x4  __attribute__((ext_vector_type(4)));
typedef unsigned short u16x4 __attribute__((ext_vector_type(4)));
typedef unsigned short u16x8 __attribute__((ext_vector_type(8)));

#define DEV static __device__ __forceinline__

constexpr int B_ = 8, T_ = 1024, C_ = 768, H_ = 12, HD_ = 64;
constexpr int M1 = B_ * T_;   // 8192
constexpr int N1 = 3 * C_;    // 2304
constexpr int KD = C_;        // 768

DEV u16 f2bf(float f) {
    union { float f; unsigned u; } v; v.f = f;
    unsigned r = v.u + 0x7fffu + ((v.u >> 16) & 1u);   // RNE
    return (u16)(r >> 16);
}

DEV u16 bfbits(float f) {  // native cast -> compiler can pair into v_cvt_pk_bf16_f32
    __bf16 h = (__bf16)f;
    union { __bf16 h; u16 u; } v; v.h = h;
    return v.u;
}

DEV void gload16(const void* g, void* l) {
    // async global->LDS, 16B/lane; LDS dest = wave-uniform base + lane*16
    __builtin_amdgcn_global_load_lds(
        (const __attribute__((address_space(1))) unsigned*)g,
        (__attribute__((address_space(3))) unsigned*)l, 16, 0, 0);
}

// ---------------- convert kernels ----------------

__global__ __launch_bounds__(256) void cvt_x_kern(const float* __restrict__ x,
                                                  u16* __restrict__ xb, int n8) {
    int i = blockIdx.x * 256 + threadIdx.x;
    if (i >= n8) return;
    const float4* xf = (const float4*)x;
    float4 a = xf[i * 2], b = xf[i * 2 + 1];
    u16x8 o;
    o[0] = f2bf(a.x); o[1] = f2bf(a.y); o[2] = f2bf(a.z); o[3] = f2bf(a.w);
    o[4] = f2bf(b.x); o[5] = f2bf(b.y); o[6] = f2bf(b.z); o[7] = f2bf(b.w);
    *(u16x8*)(xb + (size_t)i * 8) = o;
}

// W [K][N] fp32 row-major -> Wt [N][K] bf16 row-major
__global__ __launch_bounds__(256) void cvt_wT_kern(const float* __restrict__ W,
                                                   u16* __restrict__ Wt, int K, int N) {
    __shared__ float tile[32][33];
    int n0 = blockIdx.x * 32, k0 = blockIdx.y * 32;
    int tx = threadIdx.x & 31, ty = threadIdx.x >> 5;  // 32 x 8
#pragma unroll
    for (int i = 0; i < 4; i++) {
        int k = ty * 4 + i;
        tile[k][tx] = W[(size_t)(k0 + k) * N + n0 + tx];
    }
    __syncthreads();
#pragma unroll
    for (int i = 0; i < 4; i++) {
        int n = ty * 4 + i;
        Wt[(size_t)(n0 + n) * K + k0 + tx] = f2bf(tile[tx][n]);
    }
}

// ---------------- GEMM (A [M][K] bf16, Bt [N][K] bf16), 128x128 tile, BK=64 ----------------
// MODE 0: qkv epilogue (scatter q*0.125/k/vT).  MODE 1: fp32 out + bias.

template <int MODE>
__global__ __launch_bounds__(256, 2) void gemm_bt_kern(
    const u16* __restrict__ A, const u16* __restrict__ Bt,
    const float* __restrict__ bias, int nBN,
    u16* __restrict__ qw, u16* __restrict__ kw, u16* __restrict__ vw,
    float* __restrict__ out) {
    __shared__ u16 ldsA[128 * 64];
    __shared__ u16 ldsB[128 * 64];
    const int bm = blockIdx.x / nBN, bn = blockIdx.x % nBN;
    const int m0 = bm * 128, n0 = bn * 128;
    const int t = threadIdx.x;
    const int lane = t & 63, w = t >> 6;
    const int wr = w >> 1, wc = w & 1;
    const int l15 = lane & 15, lhi = lane >> 4;
    // staging: thread t covers tile-row (t>>3)+s*32, 16B chunk (t&7)
    const int srow = t >> 3;
    const int scb = ((t & 7) << 4) ^ ((srow & 7) << 4);  // pre-swizzled source chunk
    const char* Ab = (const char*)(A + (size_t)(m0 + srow) * KD) + scb;
    const char* Bb = (const char*)(Bt + (size_t)(n0 + srow) * KD) + scb;
    char* lA = (char*)ldsA + w * 1024;  // uniform wave base; HW adds lane*16
    char* lB = (char*)ldsB + w * 1024;

    f32x4 acc[4][4] = {};

    for (int k0 = 0; k0 < KD; k0 += 64) {
#pragma unroll
        for (int s = 0; s < 4; s++) {
            gload16(Ab + (size_t)k0 * 2 + (size_t)s * 32 * KD * 2, lA + s * 4096);
            gload16(Bb + (size_t)k0 * 2 + (size_t)s * 32 * KD * 2, lB + s * 4096);
        }
        __syncthreads();
#pragma unroll
        for (int kk = 0; kk < 2; kk++) {
            bf16x8 af[4], bfr[4];
#pragma unroll
            for (int i = 0; i < 4; i++) {
                int rowA = wr * 64 + i * 16 + l15;
                af[i] = *(const bf16x8*)((const char*)ldsA + rowA * 128 +
                                         ((kk * 64 + lhi * 16) ^ ((rowA & 7) << 4)));
                int rowB = wc * 64 + i * 16 + l15;
                bfr[i] = *(const bf16x8*)((const char*)ldsB + rowB * 128 +
                                          ((kk * 64 + lhi * 16) ^ ((rowB & 7) << 4)));
            }
#pragma unroll
            for (int fm = 0; fm < 4; fm++)
#pragma unroll
                for (int fn = 0; fn < 4; fn++)
                    acc[fm][fn] = __builtin_amdgcn_mfma_f32_16x16x32_bf16(
                        af[fm], bfr[fn], acc[fm][fn], 0, 0, 0);
        }
        __syncthreads();
    }

    if constexpr (MODE == 1) {
#pragma unroll
        for (int fm = 0; fm < 4; fm++) {
            const int mb = m0 + wr * 64 + fm * 16 + lhi * 4;
#pragma unroll
            for (int fn = 0; fn < 4; fn++) {
                const int n = n0 + wc * 64 + fn * 16 + l15;
                const float bv = bias[n];
#pragma unroll
                for (int r = 0; r < 4; r++)
                    out[(size_t)(mb + r) * C_ + n] = acc[fm][fn][r] + bv;
            }
        }
    } else {
#pragma unroll
        for (int fn = 0; fn < 4; fn++) {
            const int c0 = n0 + wc * 64 + fn * 16;
            const int h3 = c0 >> 6;                 // wave-uniform head index
            const int d = (c0 & 63) + l15;
            const float bv = bias[c0 + l15];
#pragma unroll
            for (int fm = 0; fm < 4; fm++) {
                const int mb = m0 + wr * 64 + fm * 16 + lhi * 4;
                const int b = mb >> 10, tq = mb & 1023;
                if (h3 < H_) {
                    u16* dst = qw + ((size_t)(b * H_ + h3) * T_ + tq) * HD_ + d;
#pragma unroll
                    for (int r = 0; r < 4; r++)
                        dst[r * HD_] = f2bf((acc[fm][fn][r] + bv) * 0.125f);
                } else if (h3 < 2 * H_) {
                    u16* dst = kw + ((size_t)(b * H_ + (h3 - H_)) * T_ + tq) * HD_ + d;
#pragma unroll
                    for (int r = 0; r < 4; r++)
                        dst[r * HD_] = f2bf(acc[fm][fn][r] + bv);
                } else {
                    u16x4 p;
#pragma unroll
                    for (int r = 0; r < 4; r++) p[r] = f2bf(acc[fm][fn][r] + bv);
                    *(u16x4*)(vw + ((size_t)(b * H_ + (h3 - 2 * H_)) * HD_ + d) * T_ + tq) = p;
                }
            }
        }
    }
}

// ---------------- causal flash attention ----------------
// 512 threads / 8 waves, QBLK=128 (16 q-rows per wave), KVBLK=64,
// double-buffered K/V, 1 barrier/tile, setprio around MFMA clusters.
// grid swizzle: same-bh blocks share bid%8 (same XCD L2); qt descending.
// q pre-scaled by 1/8.  k [bh][t][64], vT [bh][64][t], out ao [b*t][h*64+d] bf16.

__global__ __launch_bounds__(512, 4) void attn_fwd_kern(
    const u16* __restrict__ qg, const u16* __restrict__ kg,
    const u16* __restrict__ vg, u16* __restrict__ ao) {
    __shared__ u16 qld[128 * 64];
    __shared__ u16 kld[2][64 * 64];
    __shared__ u16 vld[2][64 * 64];
    __shared__ u16 pld[8][16 * 72];  // per-wave P relayout buffer (+16B pad)
    const int n = blockIdx.x;
    const int bh = (n & 7) + 8 * ((n >> 3) % 12);
    const int qt = 7 - n / 96;            // big-work blocks first
    const int t = threadIdx.x, lane = t & 63, w = t >> 6;  // w in 0..7
    const int l15 = lane & 15, lhi = lane >> 4;
    const int srow = t >> 3;              // 0..63 (512 threads cover 64 rows x 128B)
    const int scb = ((t & 7) << 4) ^ ((srow & 7) << 4);
    const char* qb = (const char*)(qg + (size_t)bh * T_ * HD_);
    const char* kb = (const char*)(kg + (size_t)bh * T_ * HD_);
    const char* vb = (const char*)(vg + (size_t)bh * HD_ * T_);

    // stage Q (128 rows = 2 x 8KB) and K/V tile 0 (8KB each)
#pragma unroll
    for (int s = 0; s < 2; s++)
        gload16(qb + (size_t)(qt * 128 + s * 64 + srow) * 128 + scb,
                (char*)qld + s * 8192 + w * 1024);
    gload16(kb + (size_t)srow * 128 + scb, (char*)kld[0] + w * 1024);
    gload16(vb + (size_t)srow * 2048 + scb, (char*)vld[0] + w * 1024);
    __syncthreads();

    f32x4 acc[4] = {};
    float mst[4] = {-1e30f, -1e30f, -1e30f, -1e30f};
    float lst[4] = {0.f, 0.f, 0.f, 0.f};

    const int ntiles = 2 * qt + 2;
    for (int kvt = 0; kvt < ntiles; kvt++) {
        const int cur = kvt & 1;
        if (kvt + 1 < ntiles) {  // prefetch next K/V tile; latency hides under compute
            gload16(kb + (size_t)((kvt + 1) * 64 + srow) * 128 + scb,
                    (char*)kld[cur ^ 1] + w * 1024);
            gload16(vb + (size_t)srow * 2048 + (kvt + 1) * 128 + scb,
                    (char*)vld[cur ^ 1] + w * 1024);
        }
        // S = Q K^T  (16 q-rows x 64 kv)
        f32x4 s4[4] = {};
        __builtin_amdgcn_s_setprio(1);
#pragma unroll
        for (int kk = 0; kk < 2; kk++) {
            const int rq = w * 16 + l15;
            bf16x8 aq = *(const bf16x8*)((const char*)qld + rq * 128 +
                                         ((kk * 64 + lhi * 16) ^ ((rq & 7) << 4)));
#pragma unroll
            for (int fc = 0; fc < 4; fc++) {
                const int rk = fc * 16 + l15;
                bf16x8 bk = *(const bf16x8*)((const char*)kld[cur] + rk * 128 +
                                             ((kk * 64 + lhi * 16) ^ ((rk & 7) << 4)));
                s4[fc] = __builtin_amdgcn_mfma_f32_16x16x32_bf16(aq, bk, s4[fc], 0, 0, 0);
            }
        }
        __builtin_amdgcn_s_setprio(0);
        const int qrow0 = qt * 128 + w * 16;
        if (kvt * 64 + 63 > qrow0) {  // diagonal-overlap tile: apply causal mask
#pragma unroll
            for (int fc = 0; fc < 4; fc++) {
                const int kcol = kvt * 64 + fc * 16 + l15;
#pragma unroll
                for (int r = 0; r < 4; r++)
                    if (kcol > qrow0 + lhi * 4 + r) s4[fc][r] = -1e30f;
            }
        }
        // online softmax (rows live in 16-lane groups)
        float rmax[4], corr[4], rsum[4];
#pragma unroll
        for (int r = 0; r < 4; r++) {
            rmax[r] = fmaxf(fmaxf(s4[0][r], s4[1][r]), fmaxf(s4[2][r], s4[3][r]));
#pragma unroll
            for (int m = 1; m < 16; m <<= 1)
                rmax[r] = fmaxf(rmax[r], __shfl_xor(rmax[r], m, 16));
            float mn = fmaxf(mst[r], rmax[r]);
            corr[r] = __expf(mst[r] - mn);
            mst[r] = mn;
        }
#pragma unroll
        for (int fc = 0; fc < 4; fc++)
#pragma unroll
            for (int r = 0; r < 4; r++)
                s4[fc][r] = __expf(s4[fc][r] - mst[r]);
#pragma unroll
        for (int r = 0; r < 4; r++) {
            rsum[r] = s4[0][r] + s4[1][r] + s4[2][r] + s4[3][r];
#pragma unroll
            for (int m = 1; m < 16; m <<= 1)
                rsum[r] += __shfl_xor(rsum[r], m, 16);
            lst[r] = lst[r] * corr[r] + rsum[r];
        }
#pragma unroll
        for (int fd = 0; fd < 4; fd++)
#pragma unroll
            for (int r = 0; r < 4; r++) acc[fd][r] *= corr[r];
        // P -> per-wave LDS region (intra-wave dep only; no barrier needed)
        u16* pw = pld[w];
#pragma unroll
        for (int fc = 0; fc < 4; fc++)
#pragma unroll
            for (int r = 0; r < 4; r++)
                pw[(lhi * 4 + r) * 72 + fc * 16 + l15] = bfbits(s4[fc][r]);
        // O += P V
        __builtin_amdgcn_s_setprio(1);
#pragma unroll
        for (int kk = 0; kk < 2; kk++) {
            bf16x8 ap = *(const bf16x8*)((const char*)pld[w] + l15 * 144 + kk * 64 + lhi * 16);
#pragma unroll
            for (int fd = 0; fd < 4; fd++) {
                const int rd = fd * 16 + l15;
                bf16x8 bv = *(const bf16x8*)((const char*)vld[cur] + rd * 128 +
                                             ((kk * 64 + lhi * 16) ^ ((rd & 7) << 4)));
                acc[fd] = __builtin_amdgcn_mfma_f32_16x16x32_bf16(ap, bv, acc[fd], 0, 0, 0);
            }
        }
        __builtin_amdgcn_s_setprio(0);
        __syncthreads();  // prefetched tile ready; all waves done with buf[cur]
    }

    const int b = bh / H_, h = bh % H_;
#pragma unroll
    for (int r = 0; r < 4; r++) {
        const int tq = qt * 128 + w * 16 + lhi * 4 + r;
        const float inv = 1.0f / lst[r];
#pragma unroll
        for (int fd = 0; fd < 4; fd++)
            ao[((size_t)(b * T_ + tq)) * C_ + h * 64 + fd * 16 + l15] =
                bfbits(acc[fd][r] * inv);
    }
}

// ---------------- launch ----------------

extern "C" void kernel_launch(void* const* d_in, const int* in_sizes, int n_in,
                              void* d_out, int out_size, void* d_ws, size_t ws_size,
                              hipStream_t stream) {
    const float* x     = (const float*)d_in[0];
    // d_in[1] = mask (causal tril) -- structure hard-coded
    const float* Wqkv  = (const float*)d_in[2];
    const float* bqkv  = (const float*)d_in[3];
    const float* Wproj = (const float*)d_in[4];
    const float* bproj = (const float*)d_in[5];
    float* out = (float*)d_out;

    char* ws = (char*)d_ws;
    u16* xb     = (u16*)(ws);                 // 12,582,912 B
    u16* wqkvT  = (u16*)(ws + 12582912);      //  3,538,944 B
    u16* wprojT = (u16*)(ws + 16121856);      //  1,179,648 B
    u16* qw     = (u16*)(ws + 17301504);      // 12,582,912 B  [B,H,T,64] (pre-scaled)
    u16* kw     = (u16*)(ws + 29884416);      // 12,582,912 B  [B,H,T,64]
    u16* vw     = (u16*)(ws + 42467328);      // 12,582,912 B  [B,H,64,T] (transposed)
    u16* ao     = (u16*)(ws + 55050240);      // 12,582,912 B  [B*T, C]

    cvt_x_kern<<<(M1 * C_ / 8 + 255) / 256, 256, 0, stream>>>(x, xb, M1 * C_ / 8);
    cvt_wT_kern<<<dim3(N1 / 32, KD / 32), 256, 0, stream>>>(Wqkv, wqkvT, KD, N1);
    cvt_wT_kern<<<dim3(C_ / 32, KD / 32), 256, 0, stream>>>(Wproj, wprojT, KD, C_);

    gemm_bt_kern<0><<<(M1 / 128) * (N1 / 128), 256, 0, stream>>>(
        xb, wqkvT, bqkv, N1 / 128, qw, kw, vw, nullptr);

    attn_fwd_kern<<<B_ * H_ * (T_ / 128), 512, 0, stream>>>(qw, kw, vw, ao);

    gemm_bt_kern<1><<<(M1 / 128) * (C_ / 128), 256, 0, stream>>>(
        ao, wprojT, bproj, C_ / 128, nullptr, nullptr, nullptr, out);
}

// Round 4
// 111.901 us; speedup vs baseline: 1.4298x; 1.1196x over previous
//
#include <hip/hip_runtime.h>

// SelfAttention fwd: qkv GEMM -> causal flash attention -> proj GEMM, bf16 MFMA.
// B=8 T=1024 C=768 H=12 HD=64.

typedef unsigned short u16;
typedef unsigned int u32;
typedef __bf16 bf16x8 __attribute__((ext_vector_type(8)));
typedef float  f32x4  __attribute__((ext_vector_type(4)));
typedef float  f32x16 __attribute__((ext_vector_type(16)));
typedef unsigned short u16x4 __attribute__((ext_vector_type(4)));
typedef unsigned short u16x8 __attribute__((ext_vector_type(8)));

#define DEV static __device__ __forceinline__

constexpr int B_ = 8, T_ = 1024, C_ = 768, H_ = 12, HD_ = 64;
constexpr int M1 = B_ * T_;   // 8192
constexpr int N1 = 3 * C_;    // 2304
constexpr int KD = C_;        // 768

DEV u16 f2bf(float f) {
    union { float f; unsigned u; } v; v.f = f;
    unsigned r = v.u + 0x7fffu + ((v.u >> 16) & 1u);   // RNE
    return (u16)(r >> 16);
}

DEV u16 bfbits(float f) {  // native cast -> v_cvt (compiler may pack)
    __bf16 h = (__bf16)f;
    union { __bf16 h; u16 u; } v; v.h = h;
    return v.u;
}

DEV void gload16(const void* g, void* l) {
    // async global->LDS, 16B/lane; LDS dest = wave-uniform base + lane*16
    __builtin_amdgcn_global_load_lds(
        (const __attribute__((address_space(1))) unsigned*)g,
        (__attribute__((address_space(3))) unsigned*)l, 16, 0, 0);
}

DEV float redmax16(f32x16 v) {
    float a0 = fmaxf(v[0], v[1]), a1 = fmaxf(v[2], v[3]);
    float a2 = fmaxf(v[4], v[5]), a3 = fmaxf(v[6], v[7]);
    float a4 = fmaxf(v[8], v[9]), a5 = fmaxf(v[10], v[11]);
    float a6 = fmaxf(v[12], v[13]), a7 = fmaxf(v[14], v[15]);
    float b0 = fmaxf(a0, a1), b1 = fmaxf(a2, a3);
    float b2 = fmaxf(a4, a5), b3 = fmaxf(a6, a7);
    return fmaxf(fmaxf(b0, b1), fmaxf(b2, b3));
}
DEV float redsum16(f32x16 v) {
    float a0 = v[0] + v[1], a1 = v[2] + v[3], a2 = v[4] + v[5], a3 = v[6] + v[7];
    float a4 = v[8] + v[9], a5 = v[10] + v[11], a6 = v[12] + v[13], a7 = v[14] + v[15];
    float b0 = a0 + a1, b1 = a2 + a3, b2 = a4 + a5, b3 = a6 + a7;
    return (b0 + b1) + (b2 + b3);
}

// ---------------- convert kernels ----------------

__global__ __launch_bounds__(256) void cvt_x_kern(const float* __restrict__ x,
                                                  u16* __restrict__ xb, int n8) {
    int i = blockIdx.x * 256 + threadIdx.x;
    if (i >= n8) return;
    const float4* xf = (const float4*)x;
    float4 a = xf[i * 2], b = xf[i * 2 + 1];
    u16x8 o;
    o[0] = f2bf(a.x); o[1] = f2bf(a.y); o[2] = f2bf(a.z); o[3] = f2bf(a.w);
    o[4] = f2bf(b.x); o[5] = f2bf(b.y); o[6] = f2bf(b.z); o[7] = f2bf(b.w);
    *(u16x8*)(xb + (size_t)i * 8) = o;
}

// W [K][N] fp32 row-major -> Wt [N][K] bf16 row-major
__global__ __launch_bounds__(256) void cvt_wT_kern(const float* __restrict__ W,
                                                   u16* __restrict__ Wt, int K, int N) {
    __shared__ float tile[32][33];
    int n0 = blockIdx.x * 32, k0 = blockIdx.y * 32;
    int tx = threadIdx.x & 31, ty = threadIdx.x >> 5;  // 32 x 8
#pragma unroll
    for (int i = 0; i < 4; i++) {
        int k = ty * 4 + i;
        tile[k][tx] = W[(size_t)(k0 + k) * N + n0 + tx];
    }
    __syncthreads();
#pragma unroll
    for (int i = 0; i < 4; i++) {
        int n = ty * 4 + i;
        Wt[(size_t)(n0 + n) * K + k0 + tx] = f2bf(tile[tx][n]);
    }
}

// ---------------- GEMM (A [M][K] bf16, Bt [N][K] bf16), 128x128 tile, BK=64 ----------------
// MODE 0: qkv epilogue (scatter q*0.125/k/vT).  MODE 1: fp32 out + bias.

template <int MODE>
__global__ __launch_bounds__(256, 2) void gemm_bt_kern(
    const u16* __restrict__ A, const u16* __restrict__ Bt,
    const float* __restrict__ bias, int nBN,
    u16* __restrict__ qw, u16* __restrict__ kw, u16* __restrict__ vw,
    float* __restrict__ out) {
    __shared__ u16 ldsA[128 * 64];
    __shared__ u16 ldsB[128 * 64];
    const int bm = blockIdx.x / nBN, bn = blockIdx.x % nBN;
    const int m0 = bm * 128, n0 = bn * 128;
    const int t = threadIdx.x;
    const int lane = t & 63, w = t >> 6;
    const int wr = w >> 1, wc = w & 1;
    const int l15 = lane & 15, lhi = lane >> 4;
    // staging: thread t covers tile-row (t>>3)+s*32, 16B chunk (t&7)
    const int srow = t >> 3;
    const int scb = ((t & 7) << 4) ^ ((srow & 7) << 4);  // pre-swizzled source chunk
    const char* Ab = (const char*)(A + (size_t)(m0 + srow) * KD) + scb;
    const char* Bb = (const char*)(Bt + (size_t)(n0 + srow) * KD) + scb;
    char* lA = (char*)ldsA + w * 1024;  // uniform wave base; HW adds lane*16
    char* lB = (char*)ldsB + w * 1024;

    f32x4 acc[4][4] = {};

    for (int k0 = 0; k0 < KD; k0 += 64) {
#pragma unroll
        for (int s = 0; s < 4; s++) {
            gload16(Ab + (size_t)k0 * 2 + (size_t)s * 32 * KD * 2, lA + s * 4096);
            gload16(Bb + (size_t)k0 * 2 + (size_t)s * 32 * KD * 2, lB + s * 4096);
        }
        __syncthreads();
#pragma unroll
        for (int kk = 0; kk < 2; kk++) {
            bf16x8 af[4], bfr[4];
#pragma unroll
            for (int i = 0; i < 4; i++) {
                int rowA = wr * 64 + i * 16 + l15;
                af[i] = *(const bf16x8*)((const char*)ldsA + rowA * 128 +
                                         ((kk * 64 + lhi * 16) ^ ((rowA & 7) << 4)));
                int rowB = wc * 64 + i * 16 + l15;
                bfr[i] = *(const bf16x8*)((const char*)ldsB + rowB * 128 +
                                          ((kk * 64 + lhi * 16) ^ ((rowB & 7) << 4)));
            }
#pragma unroll
            for (int fm = 0; fm < 4; fm++)
#pragma unroll
                for (int fn = 0; fn < 4; fn++)
                    acc[fm][fn] = __builtin_amdgcn_mfma_f32_16x16x32_bf16(
                        af[fm], bfr[fn], acc[fm][fn], 0, 0, 0);
        }
        __syncthreads();
    }

    if constexpr (MODE == 1) {
#pragma unroll
        for (int fm = 0; fm < 4; fm++) {
            const int mb = m0 + wr * 64 + fm * 16 + lhi * 4;
#pragma unroll
            for (int fn = 0; fn < 4; fn++) {
                const int n = n0 + wc * 64 + fn * 16 + l15;
                const float bv = bias[n];
#pragma unroll
                for (int r = 0; r < 4; r++)
                    out[(size_t)(mb + r) * C_ + n] = acc[fm][fn][r] + bv;
            }
        }
    } else {
#pragma unroll
        for (int fn = 0; fn < 4; fn++) {
            const int c0 = n0 + wc * 64 + fn * 16;
            const int h3 = c0 >> 6;                 // wave-uniform head index
            const int d = (c0 & 63) + l15;
            const float bv = bias[c0 + l15];
#pragma unroll
            for (int fm = 0; fm < 4; fm++) {
                const int mb = m0 + wr * 64 + fm * 16 + lhi * 4;
                const int b = mb >> 10, tq = mb & 1023;
                if (h3 < H_) {
                    u16* dst = qw + ((size_t)(b * H_ + h3) * T_ + tq) * HD_ + d;
#pragma unroll
                    for (int r = 0; r < 4; r++)
                        dst[r * HD_] = f2bf((acc[fm][fn][r] + bv) * 0.125f);
                } else if (h3 < 2 * H_) {
                    u16* dst = kw + ((size_t)(b * H_ + (h3 - H_)) * T_ + tq) * HD_ + d;
#pragma unroll
                    for (int r = 0; r < 4; r++)
                        dst[r * HD_] = f2bf(acc[fm][fn][r] + bv);
                } else {
                    u16x4 p;
#pragma unroll
                    for (int r = 0; r < 4; r++) p[r] = f2bf(acc[fm][fn][r] + bv);
                    *(u16x4*)(vw + ((size_t)(b * H_ + (h3 - 2 * H_)) * HD_ + d) * T_ + tq) = p;
                }
            }
        }
    }
}

// ---------------- causal flash attention (swapped 32x32 MFMA) ----------------
// 256 threads / 4 waves, QBLK=128 (32 q-rows per wave via 32x32x16), KVBLK=64.
// S^T = K.Q^T : each lane owns ONE q-row (col = lane&31) -> lane-local softmax,
// only 2 cross-lane shfls per tile. O^T = V^T.P^T, acc col = q matches softmax.
// Q hoisted to registers; P relayout via per-wave swizzled LDS buffer.
// q pre-scaled by 1/8.  k [bh][t][64], vT [bh][64][t], out ao [b*t][h*64+d] bf16.

__global__ __launch_bounds__(256, 3) void attn_fwd_kern(
    const u16* __restrict__ qg, const u16* __restrict__ kg,
    const u16* __restrict__ vg, u16* __restrict__ ao) {
    __shared__ u16 kld[2][64 * 64];   // K tile: rows kv, cols k (swizzled)
    __shared__ u16 vld[2][64 * 64];   // V^T tile: rows d, cols kv (swizzled)
    __shared__ u16 pld[4][32 * 64];   // per-wave P [q][kv] (swizzled)
    const int n = blockIdx.x;
    const int bh = (n & 7) + 8 * ((n >> 3) % 12);
    const int qt = 7 - n / 96;            // big-work blocks first
    const int t = threadIdx.x, lane = t & 63, w = t >> 6;
    const int q5 = lane & 31, h2 = lane >> 5;
    const int srow = t >> 3;              // 0..31
    const int scb = ((t & 7) << 4) ^ ((srow & 7) << 4);
    const char* kb = (const char*)(kg + (size_t)bh * T_ * HD_);
    const char* vb = (const char*)(vg + (size_t)bh * HD_ * T_);

    // Q -> registers (B-frags): lane covers q-row qt*128+w*32+q5, k chunks
    const int qrow_g = qt * 128 + w * 32 + q5;
    const u16* qrow = qg + (size_t)bh * T_ * HD_ + (size_t)qrow_g * HD_ + h2 * 8;
    bf16x8 qf[4];
#pragma unroll
    for (int kc = 0; kc < 4; kc++)
        qf[kc] = *(const bf16x8*)(qrow + kc * 16);

    // stage K/V tile 0
#pragma unroll
    for (int s = 0; s < 2; s++) {
        gload16(kb + (size_t)(srow + s * 32) * 128 + scb,
                (char*)kld[0] + w * 1024 + s * 4096);
        gload16(vb + (size_t)(srow + s * 32) * 2048 + scb,
                (char*)vld[0] + w * 1024 + s * 4096);
    }
    __syncthreads();

    f32x16 acc[2] = {};
    float mst = -1e30f, lst = 0.f;
    const int qmax = qt * 128 + w * 32 + 31;
    char* pw = (char*)pld[w];

    const int ntiles = 2 * qt + 2;
    for (int kvt = 0; kvt < ntiles; kvt++) {
        const int cur = kvt & 1;
        if (kvt + 1 < ntiles) {  // prefetch next K/V tile
#pragma unroll
            for (int s = 0; s < 2; s++) {
                gload16(kb + (size_t)((kvt + 1) * 64 + srow + s * 32) * 128 + scb,
                        (char*)kld[cur ^ 1] + w * 1024 + s * 4096);
                gload16(vb + (size_t)(srow + s * 32) * 2048 + (kvt + 1) * 128 + scb,
                        (char*)vld[cur ^ 1] + w * 1024 + s * 4096);
            }
        }
        if (kvt * 64 <= qmax) {  // tile has at least one visible column for this wave
            const char* kbase = (const char*)kld[cur];
            const char* vbase = (const char*)vld[cur];
            // S^T = K . Q^T   (rows kv, cols q)
            f32x16 s0 = {}, s1 = {};
            __builtin_amdgcn_s_setprio(1);
#pragma unroll
            for (int kc = 0; kc < 4; kc++) {
                const int r0 = q5, r1 = 32 + q5;
                bf16x8 kf0 = *(const bf16x8*)(kbase + r0 * 128 +
                                              ((kc * 32 + h2 * 16) ^ ((r0 & 7) << 4)));
                bf16x8 kf1 = *(const bf16x8*)(kbase + r1 * 128 +
                                              ((kc * 32 + h2 * 16) ^ ((r1 & 7) << 4)));
                s0 = __builtin_amdgcn_mfma_f32_32x32x16_bf16(kf0, qf[kc], s0, 0, 0, 0);
                s1 = __builtin_amdgcn_mfma_f32_32x32x16_bf16(kf1, qf[kc], s1, 0, 0, 0);
            }
            __builtin_amdgcn_s_setprio(0);
            // causal mask (S^T reg r -> kv = (r&3)+8*(r>>2)+4*h2)
            if (kvt * 64 + 63 > qt * 128 + w * 32) {
                const int qg_ = qrow_g, kvb0 = kvt * 64 + 4 * h2;
#pragma unroll
                for (int r = 0; r < 16; r++) {
                    const int kvo = (r & 3) + 8 * (r >> 2);
                    if (kvb0 + kvo > qg_) s0[r] = -1e30f;
                    if (kvb0 + 32 + kvo > qg_) s1[r] = -1e30f;
                }
            }
            // lane-local online softmax (lane owns q-row q5; h2 halves duplicate)
            float pmax = fmaxf(redmax16(s0), redmax16(s1));
            pmax = fmaxf(pmax, __shfl_xor(pmax, 32));
            const float mn = fmaxf(mst, pmax);
            const float corr = __expf(mst - mn);
            mst = mn;
#pragma unroll
            for (int r = 0; r < 16; r++) {
                s0[r] = __expf(s0[r] - mn);
                s1[r] = __expf(s1[r] - mn);
            }
            float rs = redsum16(s0) + redsum16(s1);
            rs += __shfl_xor(rs, 32);
            lst = lst * corr + rs;
#pragma unroll
            for (int r = 0; r < 16; r++) { acc[0][r] *= corr; acc[1][r] *= corr; }
            // P -> per-wave LDS [q][kv] (pairs; swizzled), intra-wave dep only
            const int swz = (q5 & 7) << 4;
#pragma unroll
            for (int a = 0; a < 8; a++) {
                const int kv0 = ((2 * a) & 3) + 8 * (a >> 1) + 4 * h2;
                u32 pk0 = (u32)bfbits(s0[2 * a]) | ((u32)bfbits(s0[2 * a + 1]) << 16);
                u32 pk1 = (u32)bfbits(s1[2 * a]) | ((u32)bfbits(s1[2 * a + 1]) << 16);
                *(u32*)(pw + q5 * 128 + ((kv0 * 2) ^ swz)) = pk0;
                *(u32*)(pw + q5 * 128 + (((kv0 + 32) * 2) ^ swz)) = pk1;
            }
            // O^T += V^T . P^T
            bf16x8 pf[4];
#pragma unroll
            for (int m = 0; m < 4; m++)
                pf[m] = *(const bf16x8*)(pw + q5 * 128 + ((m * 32 + h2 * 16) ^ swz));
            __builtin_amdgcn_s_setprio(1);
#pragma unroll
            for (int m = 0; m < 4; m++) {
#pragma unroll
                for (int db = 0; db < 2; db++) {
                    const int rd = db * 32 + q5;
                    bf16x8 vf = *(const bf16x8*)(vbase + rd * 128 +
                                                 ((m * 32 + h2 * 16) ^ ((rd & 7) << 4)));
                    acc[db] = __builtin_amdgcn_mfma_f32_32x32x16_bf16(vf, pf[m], acc[db], 0, 0, 0);
                }
            }
            __builtin_amdgcn_s_setprio(0);
        }
        __syncthreads();  // prefetched tile ready; all waves done with buf[cur]
    }

    // epilogue: acc[db][r] = O[q = qrow_g][d = db*32 + (r&3) + 8*(r>>2) + 4*h2]
    const int b = bh / H_, h = bh % H_;
    const float inv = 1.0f / lst;
    u16* orow = ao + (size_t)(b * T_ + qrow_g) * C_ + h * 64 + 4 * h2;
#pragma unroll
    for (int db = 0; db < 2; db++)
#pragma unroll
        for (int q2 = 0; q2 < 4; q2++) {
            u16x4 pk;
#pragma unroll
            for (int e = 0; e < 4; e++) pk[e] = bfbits(acc[db][q2 * 4 + e] * inv);
            *(u16x4*)(orow + db * 32 + q2 * 8) = pk;
        }
}

// ---------------- launch ----------------

extern "C" void kernel_launch(void* const* d_in, const int* in_sizes, int n_in,
                              void* d_out, int out_size, void* d_ws, size_t ws_size,
                              hipStream_t stream) {
    const float* x     = (const float*)d_in[0];
    // d_in[1] = mask (causal tril) -- structure hard-coded
    const float* Wqkv  = (const float*)d_in[2];
    const float* bqkv  = (const float*)d_in[3];
    const float* Wproj = (const float*)d_in[4];
    const float* bproj = (const float*)d_in[5];
    float* out = (float*)d_out;

    char* ws = (char*)d_ws;
    u16* xb     = (u16*)(ws);                 // 12,582,912 B
    u16* wqkvT  = (u16*)(ws + 12582912);      //  3,538,944 B
    u16* wprojT = (u16*)(ws + 16121856);      //  1,179,648 B
    u16* qw     = (u16*)(ws + 17301504);      // 12,582,912 B  [B,H,T,64] (pre-scaled)
    u16* kw     = (u16*)(ws + 29884416);      // 12,582,912 B  [B,H,T,64]
    u16* vw     = (u16*)(ws + 42467328);      // 12,582,912 B  [B,H,64,T] (transposed)
    u16* ao     = (u16*)(ws + 55050240);      // 12,582,912 B  [B*T, C]

    cvt_x_kern<<<(M1 * C_ / 8 + 255) / 256, 256, 0, stream>>>(x, xb, M1 * C_ / 8);
    cvt_wT_kern<<<dim3(N1 / 32, KD / 32), 256, 0, stream>>>(Wqkv, wqkvT, KD, N1);
    cvt_wT_kern<<<dim3(C_ / 32, KD / 32), 256, 0, stream>>>(Wproj, wprojT, KD, C_);

    gemm_bt_kern<0><<<(M1 / 128) * (N1 / 128), 256, 0, stream>>>(
        xb, wqkvT, bqkv, N1 / 128, qw, kw, vw, nullptr);

    attn_fwd_kern<<<B_ * H_ * (T_ / 128), 256, 0, stream>>>(qw, kw, vw, ao);

    gemm_bt_kern<1><<<(M1 / 128) * (C_ / 128), 256, 0, stream>>>(
        ao, wprojT, bproj, C_ / 128, nullptr, nullptr, nullptr, out);
}